// Round 11
// baseline (435.861 us; speedup 1.0000x reference)
//
#include <hip/hip_runtime.h>
#include <stdint.h>

#define NT 512
#define ROW 8192
#define VPT 4  // 16B vectors per thread per row
#define RPB 8  // rows per block (software-pipelined)

typedef unsigned int u32x4 __attribute__((ext_vector_type(4)));
typedef float f32x4 __attribute__((ext_vector_type(4)));

// Order-preserving float->uint transform (ascending uint == ascending float).
__device__ __forceinline__ uint32_t f2u(uint32_t b) {
    return (b & 0x80000000u) ? ~b : (b | 0x80000000u);
}
__device__ __forceinline__ uint32_t u2fbits(uint32_t u) {
    return (u & 0x80000000u) ? (u ^ 0x80000000u) : ~u;
}

// Given s_hist bin counts (higher bin index = larger value), find digit d such
// that cnt(digit > d) < k <= cnt(digit >= d).
// Writes s_sel[0] = d, s_sel[1] = k - cnt(digit > d). Ends with __syncthreads().
template <int B>
__device__ __forceinline__ void select_digit(const uint32_t* s_hist, uint32_t* s_wsum,
                                             uint32_t* s_sel, int t, uint32_t k) {
    uint32_t local = 0;
    if (B == 8) {
        uint4 h0 = ((const uint4*)s_hist)[t * 2];
        uint4 h1 = ((const uint4*)s_hist)[t * 2 + 1];
        local = h0.x + h0.y + h0.z + h0.w + h1.x + h1.y + h1.z + h1.w;
    } else {  // B == 2
        uint2 h = ((const uint2*)s_hist)[t];
        local = h.x + h.y;
    }
    const int lane = t & 63;
    const int wave = t >> 6;
    uint32_t incl = local;
#pragma unroll
    for (int off = 1; off < 64; off <<= 1) {
        uint32_t vv = __shfl_down(incl, off, 64);
        if (lane + off < 64) incl += vv;
    }
    if (lane == 0) s_wsum[wave] = incl;  // wave total
    __syncthreads();
    uint32_t later = 0;
#pragma unroll
    for (int w = 0; w < 8; ++w)
        if (w > wave) later += s_wsum[w];
    const uint32_t sfx_incl = incl + later;      // sum over groups >= t
    const uint32_t sfx_excl = sfx_incl - local;  // sum over groups >  t
    if (sfx_excl < k && k <= sfx_incl) {
        uint32_t cum = sfx_excl;
#pragma unroll
        for (int i = B - 1; i >= 0; --i) {
            uint32_t c = s_hist[t * B + i];
            if (k <= cum + c) {
                s_sel[0] = (uint32_t)(t * B + i);
                s_sel[1] = k - cum;
                break;
            }
            cum += c;
        }
    }
    __syncthreads();
}

__global__ __launch_bounds__(NT, 4) void ksparse_rowtopk(const float* __restrict__ x,
                                                         const int* __restrict__ kp,
                                                         float* __restrict__ out,
                                                         int nrows) {
    __shared__ uint32_t s_hist1[4096];  // pass1 (4096 bins); low 1024 reused by pass3
    __shared__ uint32_t s_hist2[1024];  // pass2
    __shared__ uint32_t s_wsum[8];
    __shared__ uint32_t s_sel[2];

    const int t = threadIdx.x;
    const long long row0 = (long long)blockIdx.x * RPB;

    int kin = *kp;
    if (kin < 1) kin = 1;
    if (kin > ROW) kin = ROW;
    const uint32_t k0 = (uint32_t)kin;

    u32x4 A[VPT], B[VPT];
    if (row0 < nrows) {
        const u32x4* xin = (const u32x4*)(x + row0 * ROW);
#pragma unroll
        for (int j = 0; j < VPT; ++j) A[j] = __builtin_nontemporal_load(&xin[j * NT + t]);
    }

#pragma unroll
    for (int r = 0; r < RPB; ++r) {
        const long long row = row0 + r;
        // ---- prefetch next row (loads stay in flight through this row's select)
        if (r + 1 < RPB && row + 1 < nrows) {
            const u32x4* xn = (const u32x4*)(x + (row + 1) * ROW);
#pragma unroll
            for (int j = 0; j < VPT; ++j) B[j] = __builtin_nontemporal_load(&xn[j * NT + t]);
        }
        if (row < nrows) {
            // ---- zero histograms (dirty from previous row)
            ((uint4*)s_hist1)[t] = make_uint4(0u, 0u, 0u, 0u);
            ((uint4*)s_hist1)[t + NT] = make_uint4(0u, 0u, 0u, 0u);
            if (t < 256) ((uint4*)s_hist2)[t] = make_uint4(0u, 0u, 0u, 0u);
            __syncthreads();

            uint32_t k = k0;

            // ---- pass 1: top 12 bits, 4096 bins
#pragma unroll
            for (int j = 0; j < VPT; ++j) {
                A[j].x = f2u(A[j].x);
                A[j].y = f2u(A[j].y);
                A[j].z = f2u(A[j].z);
                A[j].w = f2u(A[j].w);
                atomicAdd(&s_hist1[A[j].x >> 20], 1u);
                atomicAdd(&s_hist1[A[j].y >> 20], 1u);
                atomicAdd(&s_hist1[A[j].z >> 20], 1u);
                atomicAdd(&s_hist1[A[j].w >> 20], 1u);
            }
            __syncthreads();
            select_digit<8>(s_hist1, s_wsum, s_sel, t, k);
            const uint32_t d1 = s_sel[0];
            k = s_sel[1];

            // ---- pass 2: bits [19:10]; clear s_hist1 low 1024 for pass 3
            if (t < 256) ((uint4*)s_hist1)[t] = make_uint4(0u, 0u, 0u, 0u);
#pragma unroll
            for (int j = 0; j < VPT; ++j) {
                if ((A[j].x >> 20) == d1) atomicAdd(&s_hist2[(A[j].x >> 10) & 1023u], 1u);
                if ((A[j].y >> 20) == d1) atomicAdd(&s_hist2[(A[j].y >> 10) & 1023u], 1u);
                if ((A[j].z >> 20) == d1) atomicAdd(&s_hist2[(A[j].z >> 10) & 1023u], 1u);
                if ((A[j].w >> 20) == d1) atomicAdd(&s_hist2[(A[j].w >> 10) & 1023u], 1u);
            }
            __syncthreads();
            select_digit<2>(s_hist2, s_wsum, s_sel, t, k);
            const uint32_t d2 = s_sel[0];
            k = s_sel[1];

            // ---- pass 3: bits [9:0] into s_hist1[0:1024]
            const uint32_t pfx2 = (d1 << 10) | d2;
#pragma unroll
            for (int j = 0; j < VPT; ++j) {
                if ((A[j].x >> 10) == pfx2) atomicAdd(&s_hist1[A[j].x & 1023u], 1u);
                if ((A[j].y >> 10) == pfx2) atomicAdd(&s_hist1[A[j].y & 1023u], 1u);
                if ((A[j].z >> 10) == pfx2) atomicAdd(&s_hist1[A[j].z & 1023u], 1u);
                if ((A[j].w >> 10) == pfx2) atomicAdd(&s_hist1[A[j].w & 1023u], 1u);
            }
            __syncthreads();
            select_digit<2>(s_hist1, s_wsum, s_sel, t, k);
            const uint32_t d3 = s_sel[0];

            const uint32_t thr = (d1 << 20) | (d2 << 10) | d3;  // uint of kth value

            // ---- output: keep if u >= thr (== float compare via monotone transform)
            f32x4* orow = (f32x4*)(out + row * ROW);
#pragma unroll
            for (int j = 0; j < VPT; ++j) {
                f32x4 o;
                o.x = (A[j].x >= thr) ? __uint_as_float(u2fbits(A[j].x)) : 0.0f;
                o.y = (A[j].y >= thr) ? __uint_as_float(u2fbits(A[j].y)) : 0.0f;
                o.z = (A[j].z >= thr) ? __uint_as_float(u2fbits(A[j].z)) : 0.0f;
                o.w = (A[j].w >= thr) ? __uint_as_float(u2fbits(A[j].w)) : 0.0f;
                __builtin_nontemporal_store(o, &orow[j * NT + t]);
            }
        }
        // ---- rotate double buffer (first read of B => vmcnt wait lands HERE)
        if (r + 1 < RPB) {
#pragma unroll
            for (int j = 0; j < VPT; ++j) A[j] = B[j];
        }
    }
}

extern "C" void kernel_launch(void* const* d_in, const int* in_sizes, int n_in,
                              void* d_out, int out_size, void* d_ws, size_t ws_size,
                              hipStream_t stream) {
    const float* x = (const float*)d_in[0];
    const int* kp = (const int*)d_in[1];
    float* out = (float*)d_out;
    const int rows = in_sizes[0] / ROW;                   // 8192
    const int grid = (rows + RPB - 1) / RPB;              // 1024
    ksparse_rowtopk<<<dim3(grid), dim3(NT), 0, stream>>>(x, kp, out, rows);
}